// Round 14
// baseline (150.573 us; speedup 1.0000x reference)
//
#include <hip/hip_runtime.h>
#include <math.h>

#define T_STEPS 730
#define NB      1000
#define LENF    15
#define NEARZ   1e-5f
#define TPAD    736            // per-lane row stride (floats); 730 rounded to x16B
#define NLANES  8000           // 1000 basins x 8 members

// ===========================================================================
// PASS A: serial S/G recurrence, TWO independent chains per thread (basin b
// and b+500). R12 post-mortem: per-step cost is dominated by the serial
// add->fma->fma->max->sqrt->sub->mul chain latency (~60-90cyc incl. trans);
// with 1 wave/SIMD nothing fills it. Chain-B's instructions fill chain-A's
// latency (pure ILP). Skeleton = R11's proven shape: 6x8-step chunks/group,
// 3-buffer rotation prefetched 2 chunks ahead (sched_barrier-pinned), double
// ring + inline dwordx4 flush every 4 steps (store->overwrite = 13 steps).
// ===========================================================================
#define STEPA2(CV1, CV2, Q, SIDX)                                              \
  {                                                                            \
    float W1  = (CV1).x + S1;                                                  \
    float t1  = fmaf(W1, inv2a1, pb2a1);                                       \
    float d1  = fmaf(t1, t1, -(W1 * boa1));                                    \
    float rt1 = __builtin_amdgcn_sqrtf(fmaxf(d1, NEARZ));                      \
    float Y1  = t1 - rt1;                                                      \
    float e1  = __builtin_amdgcn_exp2f((CV1).y * ninvbl21);                    \
    float Sn1 = Y1 * e1;                                                       \
    float Gn1 = fmaf(pc1, W1 - Y1, G1) * inv1pd1;                              \
    S1 = Sn1; G1 = Gn1;                                                        \
    float W2  = (CV2).x + S2;                                                  \
    float t2  = fmaf(W2, inv2a2, pb2a2);                                       \
    float d2  = fmaf(t2, t2, -(W2 * boa2));                                    \
    float rt2 = __builtin_amdgcn_sqrtf(fmaxf(d2, NEARZ));                      \
    float Y2  = t2 - rt2;                                                      \
    float e2  = __builtin_amdgcn_exp2f((CV2).y * ninvbl22);                    \
    float Sn2 = Y2 * e2;                                                       \
    float Gn2 = fmaf(pc2, W2 - Y2, G2) * inv1pd2;                              \
    S2 = Sn2; G2 = Gn2;                                                        \
    sr1[(Q)] = Sn1; gr1[(Q)] = Gn1;                                            \
    sr2[(Q)] = Sn2; gr2[(Q)] = Gn2;                                            \
    if (((Q) & 3) == 3) {                                                      \
      *(float4*)(pS1 + (SIDX) - 3) =                                           \
          make_float4(sr1[(Q)-3], sr1[(Q)-2], sr1[(Q)-1], sr1[(Q)]);           \
      *(float4*)(pG1 + (SIDX) - 3) =                                           \
          make_float4(gr1[(Q)-3], gr1[(Q)-2], gr1[(Q)-1], gr1[(Q)]);           \
      *(float4*)(pS2 + (SIDX) - 3) =                                           \
          make_float4(sr2[(Q)-3], sr2[(Q)-2], sr2[(Q)-1], sr2[(Q)]);           \
      *(float4*)(pG2 + (SIDX) - 3) =                                           \
          make_float4(gr2[(Q)-3], gr2[(Q)-2], gr2[(Q)-1], gr2[(Q)]);           \
    }                                                                          \
  }

#define PF2(B1_, B2_, CI)                                                      \
  _Pragma("unroll")                                                            \
  for (int j = 0; j < 8; ++j) {                                                \
      int tt = (CI) * 8 + j;                                                   \
      tt = tt < T_STEPS ? tt : (T_STEPS - 1);                                  \
      B1_[j] = xf[tt * NB + b1];                                               \
      B2_[j] = xf[tt * NB + b2];                                               \
  }                                                                            \
  __builtin_amdgcn_sched_barrier(0);

__global__ __launch_bounds__(64, 1) void scan_state(const float* __restrict__ x,
                                                    const float* __restrict__ raw,
                                                    float* __restrict__ snp,
                                                    float* __restrict__ gnp) {
    const int L    = threadIdx.x;
    int gid = blockIdx.x * 64 + L;         // 0..4031 (63 blocks)
    gid = gid < 4000 ? gid : 3999;         // dup threads write identical data
    const int g2  = gid + 4000;
    const int b1  = gid >> 3;              // 0..499
    const int m   = gid & 7;               // same member for both chains
    const int b2  = b1 + 500;

    // raw layout (B,34) = [a(8), b(8), c(8), d(8), ra, rb]
    const float* rp1 = raw + b1 * 34;
    const float* rp2 = raw + b2 * 34;
    float pa1 = rp1[m] * 0.9f + 0.1f;
    float pb1 = rp1[8 + m] * 450.0f + 50.0f;
    float pc1 = rp1[16 + m];
    float pd1 = rp1[24 + m] * 0.89f + 0.01f;
    float pa2 = rp2[m] * 0.9f + 0.1f;
    float pb2 = rp2[8 + m] * 450.0f + 50.0f;
    float pc2 = rp2[16 + m];
    float pd2 = rp2[24 + m] * 0.89f + 0.01f;

    float inv2a1   = 1.0f / (2.0f * pa1);
    float pb2a1    = pb1 * inv2a1;
    float boa1     = pb1 / pa1;
    float ninvbl21 = -1.4426950408889634f / pb1;
    float inv1pd1  = 1.0f / (1.0f + pd1);
    float inv2a2   = 1.0f / (2.0f * pa2);
    float pb2a2    = pb2 * inv2a2;
    float boa2     = pb2 / pa2;
    float ninvbl22 = -1.4426950408889634f / pb2;
    float inv1pd2  = 1.0f / (1.0f + pd2);

    float* pS1 = snp + (size_t)gid * TPAD;
    float* pG1 = gnp + (size_t)gid * TPAD;
    float* pS2 = snp + (size_t)g2 * TPAD;
    float* pG2 = gnp + (size_t)g2 * TPAD;

    float S1 = 50.0f, G1 = 10.0f, S2 = 50.0f, G2 = 10.0f;
    float sr1[16], gr1[16], sr2[16], gr2[16];   // double rings

    const float2* __restrict__ xf = (const float2*)x;   // (T,B) of (p,pet)

    float2 A1[8], B1[8], C1[8], A2[8], B2[8], C2[8];
    PF2(A1, A2, 0)
    PF2(B1, B2, 1)

    // 15 iterations x 48 steps (6 chunks of 8; 48 % 16 == 0 -> static ring
    // phase) = 720 steps, then 10-step tail.
    for (int g = 0; g < 15; ++g) {
        const int c0 = 6 * g;
        PF2(C1, C2, c0 + 2)
#pragma unroll
        for (int j = 0; j < 8; ++j) STEPA2(A1[j], A2[j], j,      j)
        PF2(A1, A2, c0 + 3)
#pragma unroll
        for (int j = 0; j < 8; ++j) STEPA2(B1[j], B2[j], 8 + j,  8 + j)
        PF2(B1, B2, c0 + 4)
#pragma unroll
        for (int j = 0; j < 8; ++j) STEPA2(C1[j], C2[j], j,      16 + j)
        PF2(C1, C2, c0 + 5)
#pragma unroll
        for (int j = 0; j < 8; ++j) STEPA2(A1[j], A2[j], 8 + j,  24 + j)
        PF2(A1, A2, c0 + 6)
#pragma unroll
        for (int j = 0; j < 8; ++j) STEPA2(B1[j], B2[j], j,      32 + j)
        PF2(B1, B2, c0 + 7)
#pragma unroll
        for (int j = 0; j < 8; ++j) STEPA2(C1[j], C2[j], 8 + j,  40 + j)
        pS1 += 48; pG1 += 48; pS2 += 48; pG2 += 48;
    }
    // tail: A = chunk 90 (t=720..727), B = clamped chunk 91 (B[0]=728,B[1]=729)
#pragma unroll
    for (int j = 0; j < 8; ++j) STEPA2(A1[j], A2[j], j, j)
    STEPA2(B1[0], B2[0], 8, 8)
    STEPA2(B1[1], B2[1], 9, 9)
    *(float2*)(pS1 + 8) = make_float2(sr1[8], sr1[9]);
    *(float2*)(pG1 + 8) = make_float2(gr1[8], gr1[9]);
    *(float2*)(pS2 + 8) = make_float2(sr2[8], sr2[9]);
    *(float2*)(pG2 + 8) = make_float2(gr2[8], gr2[9]);
}

// ===========================================================================
// PASS B: t-parallel finalize (unchanged from R12). Block = 256 = one
// (t-tile, basin); grid (3,1000). UH weights once per block into LDS;
// reconstruct Y = Sn*exp2(+pet/b); means over m -> ch3..5; qs/qg staged in
// LDS (tile + 14 halo); 15-tap gamma-UH conv -> ch0..2 (ch0 = ch1+ch2).
// ===========================================================================
__global__ __launch_bounds__(256) void finalize(const float* __restrict__ x,
                                                const float* __restrict__ raw,
                                                const float* __restrict__ snp,
                                                const float* __restrict__ gnp,
                                                float* __restrict__ out) {
    __shared__ float qs_sh[270], qg_sh[270], w_sh[16];

    const int b     = blockIdx.y;
    const int tbase = blockIdx.x * 256;
    const int tid   = threadIdx.x;

    const float* rp = raw + b * 34;

    if (tid < LENF) {
        float ra = rp[32] * 2.9f;
        float rb = rp[33] * 6.5f;
        float aa = fmaxf(ra, 0.0f) + 0.1f;
        float th = fmaxf(rb, 0.0f) + 0.5f;
        float tk = (float)tid + 0.5f;
        w_sh[tid] = __expf((aa - 1.0f) * __logf(tk) - tk / th);
    }

    float e2s[8], omc_[8], d_[8];
#pragma unroll
    for (int m = 0; m < 8; ++m) {
        float pb = rp[8 + m] * 450.0f + 50.0f;
        e2s[m]  = 1.4426950408889634f / pb;     // Y = Sn * exp2(pet * e2s)
        omc_[m] = 1.0f - rp[16 + m];
        d_[m]   = rp[24 + m] * 0.89f + 0.01f;
    }

    const float2* __restrict__ xf = (const float2*)x;

#pragma unroll
    for (int it = 0; it < 2; ++it) {
        int idx = tid + it * 256;
        if (idx < 270) {
            int tt = tbase + idx - 14;
            float qs = 0.0f, qg = 0.0f;
            if (tt >= 0 && tt < T_STEPS) {
                float2 pc2 = xf[tt * NB + b];
                float p = pc2.x, pet = pc2.y;
                float aet = 0.0f, ssum = 0.0f, gsum = 0.0f;
                int tprev = tt > 0 ? tt - 1 : 0;
#pragma unroll
                for (int m = 0; m < 8; ++m) {
                    const float* rowS = snp + (size_t)(b * 8 + m) * TPAD;
                    const float* rowG = gnp + (size_t)(b * 8 + m) * TPAD;
                    float sn = rowS[tt];
                    float sp = tt > 0 ? rowS[tprev] : 50.0f;
                    float gn = rowG[tt];
                    float y  = sn * __builtin_amdgcn_exp2f(pet * e2s[m]);
                    float avail = (p + sp) - y;
                    qs   += omc_[m] * avail;
                    qg   += d_[m] * gn;
                    aet  += y - sn;
                    ssum += sn;
                    gsum += gn;
                }
                if (idx >= 14) {
                    float* o = out + ((size_t)tt * NB + b) * 6;
                    o[3] = aet * 0.125f;
                    o[4] = ssum * 0.125f;
                    o[5] = gsum * 0.125f;
                }
            }
            qs_sh[idx] = qs;
            qg_sh[idx] = qg;
        }
    }
    __syncthreads();

    const int t = tbase + tid;
    if (t >= T_STEPS) return;

    float sw = 0.0f;
#pragma unroll
    for (int k = 0; k < LENF; ++k) sw += w_sh[k];
    float invs = 0.125f / sw;
    float ys = 0.0f, yg = 0.0f;
#pragma unroll
    for (int k = 0; k < LENF; ++k) {
        float wk = w_sh[k] * invs;
        ys = fmaf(qs_sh[tid + 14 - k], wk, ys);
        yg = fmaf(qg_sh[tid + 14 - k], wk, yg);
    }
    float* o = out + ((size_t)t * NB + b) * 6;
    o[0] = ys + yg;
    o[1] = ys;
    o[2] = yg;
}

// ===========================================================================
// ws layout: snp[8000][736] | gnp[8000][736] = 47.1 MB (harness ws is 268 MB
// -- observed via the 262144 KB poison fills in R11/R12 profiles).
// ===========================================================================
extern "C" void kernel_launch(void* const* d_in, const int* in_sizes, int n_in,
                              void* d_out, int out_size, void* d_ws, size_t ws_size,
                              hipStream_t stream) {
    const float* x   = (const float*)d_in[0];   // (T,B,2) fp32
    const float* raw = (const float*)d_in[1];   // (B,34)  fp32
    float* out = (float*)d_out;                 // (T,B,6) fp32

    float* snp = (float*)d_ws;
    float* gnp = snp + (size_t)NLANES * TPAD;

    scan_state<<<dim3(63),    dim3(64),  0, stream>>>(x, raw, snp, gnp);
    finalize  <<<dim3(3, NB), dim3(256), 0, stream>>>(x, raw, snp, gnp, out);
}